// Round 1
// baseline (637.596 us; speedup 1.0000x reference)
//
#include <hip/hip_runtime.h>

typedef short s16x8 __attribute__((ext_vector_type(8)));
typedef float f32x4 __attribute__((ext_vector_type(4)));
typedef unsigned short u16x8 __attribute__((ext_vector_type(8)));

__device__ __forceinline__ float bf2f(unsigned short u){
  union { unsigned int i; float f; } v; v.i = ((unsigned int)u) << 16; return v.f;
}
__device__ __forceinline__ unsigned short f2bf(float f){
  union { float f; unsigned int i; } v; v.f = f;
  unsigned int x = v.i;
  return (unsigned short)((x + 0x7fffu + ((x >> 16) & 1u)) >> 16);
}

#define LDA_S 40  // padded LDS row stride (shorts) to break b128 bank conflicts

// out[M][N] = (A[M][K] @ W[N][K]^T + bias[N]) * scale ; OUT_BF16 picks store type
template<int OUT_BF16>
__global__ __launch_bounds__(256) void gemm_bt(
    const float* __restrict__ A, const float* __restrict__ W,
    const float* __restrict__ bias, float scale, void* __restrict__ out_,
    int M, int N, int K)
{
  __shared__ short As[128*LDA_S];
  __shared__ short Bs[128*LDA_S];
  const int bm = blockIdx.x, bn = blockIdx.y;
  const int t = threadIdx.x;
  const int wid = t >> 6, lane = t & 63;
  const int wm = wid >> 1, wn = wid & 1;

  f32x4 acc[4][4];
  #pragma unroll
  for (int m=0;m<4;m++)
    #pragma unroll
    for (int n=0;n<4;n++) acc[m][n] = (f32x4){0.f,0.f,0.f,0.f};

  const int arow = t >> 1, acb = (t & 1) * 16;
  const float* Ap = A + (size_t)(bm*128 + arow) * K + acb;
  const float* Wp = W + (size_t)(bn*128 + arow) * K + acb;
  short* asd = &As[arow*LDA_S + acb];
  short* bsd = &Bs[arow*LDA_S + acb];

  for (int k0 = 0; k0 < K; k0 += 32){
    __syncthreads();
    float ta[16], tb[16];
    #pragma unroll
    for (int j=0;j<16;j+=4){
      *(float4*)&ta[j] = *(const float4*)(Ap + k0 + j);
      *(float4*)&tb[j] = *(const float4*)(Wp + k0 + j);
    }
    s16x8 pa0, pa1, pb0, pb1;
    #pragma unroll
    for (int j=0;j<8;j++){
      pa0[j] = (short)f2bf(ta[j]);   pa1[j] = (short)f2bf(ta[8+j]);
      pb0[j] = (short)f2bf(tb[j]);   pb1[j] = (short)f2bf(tb[8+j]);
    }
    *(s16x8*)asd = pa0; *(s16x8*)(asd+8) = pa1;
    *(s16x8*)bsd = pb0; *(s16x8*)(bsd+8) = pb1;
    __syncthreads();

    const int kk = (lane >> 4) * 8;
    s16x8 af[4], bw[4];
    #pragma unroll
    for (int m=0;m<4;m++)
      af[m] = *(const s16x8*)&As[(wm*64 + m*16 + (lane&15))*LDA_S + kk];
    #pragma unroll
    for (int n=0;n<4;n++)
      bw[n] = *(const s16x8*)&Bs[(wn*64 + n*16 + (lane&15))*LDA_S + kk];
    #pragma unroll
    for (int m=0;m<4;m++)
      #pragma unroll
      for (int n=0;n<4;n++)
        acc[m][n] = __builtin_amdgcn_mfma_f32_16x16x32_bf16(af[m], bw[n], acc[m][n], 0, 0, 0);
  }

  #pragma unroll
  for (int n=0;n<4;n++){
    const int gcol = bn*128 + wn*64 + n*16 + (lane & 15);
    const float bv = bias[gcol];
    #pragma unroll
    for (int m=0;m<4;m++){
      const int growb = bm*128 + wm*64 + m*16 + (lane>>4)*4;
      #pragma unroll
      for (int r=0;r<4;r++){
        float v = (acc[m][n][r] + bv) * scale;
        size_t idx = (size_t)(growb + r) * N + gcol;
        if (OUT_BF16) ((unsigned short*)out_)[idx] = f2bf(v);
        else          ((float*)out_)[idx] = v;
      }
    }
  }
}

// partial scores over one ww-chunk: part[wwc][b*512+dd][m] = sum_{ww in chunk} Qp[b,ww,dd]*Kp[b,ww,m,dd]
__global__ __launch_bounds__(256) void scores_kernel(
    const float* __restrict__ Qp, const unsigned short* __restrict__ Kp,
    float* __restrict__ part)
{
  const int wwc = blockIdx.x, ddt = blockIdx.y, b = blockIdx.z;
  const int ww0 = wwc*64, dd0 = ddt*64;
  __shared__ float qs[64][64];
  const int t = threadIdx.x;
  {
    const int dd = t & 63, wbase = t >> 6;
    #pragma unroll
    for (int i=0;i<16;i++){
      int ww = wbase + i*4;
      qs[ww][dd] = Qp[(size_t)(b*512 + ww0 + ww)*512 + dd0 + dd];
    }
  }
  __syncthreads();
  const int g = t & 7, mr = t >> 3;
  float acc[2][8];
  #pragma unroll
  for (int r=0;r<2;r++)
    #pragma unroll
    for (int j=0;j<8;j++) acc[r][j] = 0.f;

  for (int ww=0; ww<64; ww++){
    float4 q0 = *(const float4*)&qs[ww][g*8];
    float4 q1 = *(const float4*)&qs[ww][g*8+4];
    float qv[8] = {q0.x,q0.y,q0.z,q0.w,q1.x,q1.y,q1.z,q1.w};
    #pragma unroll
    for (int r=0;r<2;r++){
      const int m = mr + r*32;
      u16x8 kv = *(const u16x8*)&Kp[((size_t)(b*512 + ww0 + ww)*64 + m)*512 + dd0 + g*8];
      #pragma unroll
      for (int j=0;j<8;j++) acc[r][j] += qv[j] * bf2f(kv[j]);
    }
  }
  #pragma unroll
  for (int r=0;r<2;r++){
    const int m = mr + r*32;
    #pragma unroll
    for (int j=0;j<8;j++){
      const int dd = dd0 + g*8 + j;
      part[(size_t)wwc*131072 + (size_t)(b*512 + dd)*64 + m] = acc[r][j];
    }
  }
}

// reduce 8 partials + softmax over m (one wave per (b,dd) row)
__global__ __launch_bounds__(256) void softmax_kernel(
    const float* __restrict__ part, float* __restrict__ attn)
{
  const int row = blockIdx.x*4 + (threadIdx.x >> 6);  // 0..2047
  const int m = threadIdx.x & 63;
  float v = 0.f;
  #pragma unroll
  for (int c=0;c<8;c++) v += part[(size_t)c*131072 + (size_t)row*64 + m];
  float mx = v;
  #pragma unroll
  for (int o=32;o>=1;o>>=1) mx = fmaxf(mx, __shfl_xor(mx, o));
  float e = __expf(v - mx);
  float s = e;
  #pragma unroll
  for (int o=32;o>=1;o>>=1) s += __shfl_xor(s, o);
  attn[(size_t)row*64 + m] = e / s;
}

// out_att[(ww*4+b)][dd] = sum_m attn[b,dd,m] * Vp[b,ww,m,dd]
__global__ __launch_bounds__(256) void pv_kernel(
    const float* __restrict__ attn, const unsigned short* __restrict__ Vp,
    float* __restrict__ att_out)
{
  const int wwc = blockIdx.x, ddt = blockIdx.y, b = blockIdx.z;
  const int ww0 = wwc*64, dd0 = ddt*64;
  __shared__ float as_[64][72];   // [m][dd], padded
  const int t = threadIdx.x;
  {
    const int m = t & 63, dbase = t >> 6;
    #pragma unroll
    for (int i=0;i<16;i++){
      int dd = dbase + i*4;
      as_[m][dd] = attn[(size_t)(b*512 + dd0 + dd)*64 + m];
    }
  }
  __syncthreads();
  const int g = t & 7, wr = t >> 3;
  float acc[2][8];
  #pragma unroll
  for (int r=0;r<2;r++)
    #pragma unroll
    for (int j=0;j<8;j++) acc[r][j] = 0.f;

  for (int m=0;m<64;m++){
    float4 a0 = *(const float4*)&as_[m][g*8];
    float4 a1 = *(const float4*)&as_[m][g*8+4];
    float av[8] = {a0.x,a0.y,a0.z,a0.w,a1.x,a1.y,a1.z,a1.w};
    #pragma unroll
    for (int r=0;r<2;r++){
      const int ww = wr + r*32;
      u16x8 vv = *(const u16x8*)&Vp[((size_t)(b*512 + ww0 + ww)*64 + m)*512 + dd0 + g*8];
      #pragma unroll
      for (int j=0;j<8;j++) acc[r][j] += av[j] * bf2f(vv[j]);
    }
  }
  #pragma unroll
  for (int r=0;r<2;r++){
    const int ww = ww0 + wr + r*32;
    float4 o0 = {acc[r][0],acc[r][1],acc[r][2],acc[r][3]};
    float4 o1 = {acc[r][4],acc[r][5],acc[r][6],acc[r][7]};
    float* dst = &att_out[(size_t)(ww*4 + b)*512 + dd0 + g*8];
    *(float4*)dst = o0;
    *(float4*)(dst+4) = o1;
  }
}

extern "C" void kernel_launch(void* const* d_in, const int* in_sizes, int n_in,
                              void* d_out, int out_size, void* d_ws, size_t ws_size,
                              hipStream_t stream) {
  const float* Q  = (const float*)d_in[0];
  const float* K  = (const float*)d_in[1];
  const float* V  = (const float*)d_in[2];
  const float* Wq = (const float*)d_in[3];
  const float* bq = (const float*)d_in[4];
  const float* Wk = (const float*)d_in[5];
  const float* bk = (const float*)d_in[6];
  const float* Wv = (const float*)d_in[7];
  const float* bv = (const float*)d_in[8];
  const float* Wp = (const float*)d_in[9];
  const float* bp = (const float*)d_in[10];
  float* out = (float*)d_out;

  char* ws = (char*)d_ws;
  float* Qp             = (float*)(ws);                      // 2048x512 f32 = 4 MB
  float* att_out        = (float*)(ws + ((size_t)4<<20));    // 2048x512 f32 = 4 MB
  float* part           = (float*)(ws + ((size_t)8<<20));    // 8x2048x64 f32 = 4 MB
  float* attn           = (float*)(ws + ((size_t)12<<20));   // 2048x64 f32 = 0.5 MB
  unsigned short* KVp   = (unsigned short*)(ws + ((size_t)13<<20)); // 131072x512 bf16 = 128 MiB

  const float qscale = 0.044194173824159223f;  // 1/sqrt(512)

  // Q projection (+bias, then /sqrt(d)), f32 out
  gemm_bt<0><<<dim3(16,4), 256, 0, stream>>>(Q, Wq, bq, qscale, Qp, 2048, 512, 512);
  // K projection, bf16 out
  gemm_bt<1><<<dim3(1024,4), 256, 0, stream>>>(K, Wk, bk, 1.f, KVp, 131072, 512, 512);
  // scores partials + softmax
  scores_kernel<<<dim3(8,8,4), 256, 0, stream>>>(Qp, KVp, part);
  softmax_kernel<<<512, 256, 0, stream>>>(part, attn);
  // V projection reuses the KVp buffer (stream-ordered after scores)
  gemm_bt<1><<<dim3(1024,4), 256, 0, stream>>>(V, Wv, bv, 1.f, KVp, 131072, 512, 512);
  // PV -> rows in (ww*4+b) order
  pv_kernel<<<dim3(8,8,4), 256, 0, stream>>>(attn, KVp, att_out);
  // output projection straight into d_out
  gemm_bt<0><<<dim3(16,4), 256, 0, stream>>>(att_out, Wp, bp, 1.f, out, 2048, 512, 512);
}

// Round 2
// 487.590 us; speedup vs baseline: 1.3076x; 1.3076x over previous
//
#include <hip/hip_runtime.h>
#include <hip/hip_bf16.h>

typedef short s16x8 __attribute__((ext_vector_type(8)));
typedef float f32x4 __attribute__((ext_vector_type(4)));
typedef unsigned short u16x8 __attribute__((ext_vector_type(8)));

__device__ __forceinline__ float bf2f(unsigned short u){
  union { unsigned int i; float f; } v; v.i = ((unsigned int)u) << 16; return v.f;
}
__device__ __forceinline__ unsigned short f2bf(float f){
  union { float f; unsigned int i; } v; v.f = f;
  unsigned int x = v.i;
  return (unsigned short)((x + 0x7fffu + ((x >> 16) & 1u)) >> 16);
}
__device__ __forceinline__ short f2bs(float f){
  union { __hip_bfloat16 h; short s; } u; u.h = __float2bfloat16(f); return u.s;
}
__device__ __forceinline__ s16x8 cvt8(f32x4 a, f32x4 b){
  s16x8 r;
  r[0]=f2bs(a[0]); r[1]=f2bs(a[1]); r[2]=f2bs(a[2]); r[3]=f2bs(a[3]);
  r[4]=f2bs(b[0]); r[5]=f2bs(b[1]); r[6]=f2bs(b[2]); r[7]=f2bs(b[3]);
  return r;
}

__device__ __forceinline__ void gload16(const void* g, void* l){
  __builtin_amdgcn_global_load_lds(
      (__attribute__((address_space(1))) void*)(g),
      (__attribute__((address_space(3))) void*)(l), 16, 0, 0);
}

// cast the 4 weight matrices (512x512 f32) to bf16 in one launch
__global__ __launch_bounds__(256) void cast_w(
    const float* __restrict__ w0, const float* __restrict__ w1,
    const float* __restrict__ w2, const float* __restrict__ w3,
    unsigned short* __restrict__ o0, unsigned short* __restrict__ o1,
    unsigned short* __restrict__ o2, unsigned short* __restrict__ o3)
{
  int g = blockIdx.x * 256 + threadIdx.x;      // 131072 threads total
  int which = g >> 15;
  int off = (g & 32767) * 8;
  const float* src = which==0 ? w0 : which==1 ? w1 : which==2 ? w2 : w3;
  unsigned short* dst = which==0 ? o0 : which==1 ? o1 : which==2 ? o2 : o3;
  float4 a = *(const float4*)(src + off);
  float4 b = *(const float4*)(src + off + 4);
  u16x8 r;
  r[0]=f2bf(a.x); r[1]=f2bf(a.y); r[2]=f2bf(a.z); r[3]=f2bf(a.w);
  r[4]=f2bf(b.x); r[5]=f2bf(b.y); r[6]=f2bf(b.z); r[7]=f2bf(b.w);
  *(u16x8*)(dst + off) = r;
}

// out[M][512] = (A_f32[M][512] @ Wb_bf16[512][512]^T + bias) * scale
// A staged raw f32 via global_load_lds (XOR-swizzled), cvt->bf16 at frag read.
// BM=BN=128, BK=32, 4 waves, double-buffered, 1 barrier / K-step.
template<int OUT_BF16>
__global__ __launch_bounds__(256) void gemm_f32a(
    const float* __restrict__ A, const unsigned short* __restrict__ Wb,
    const float* __restrict__ bias, float scale, void* __restrict__ out_, int M)
{
  constexpr int K = 512, N = 512;
  __shared__ float As[2][128*32];          // 2 x 16 KB (f32)
  __shared__ unsigned short Bs[2][128*32]; // 2 x 8 KB (bf16)

  const int nwg = gridDim.x;               // multiple of 8
  const int bid = blockIdx.x;
  const int wgid = (bid & 7) * (nwg >> 3) + (bid >> 3);  // bijective XCD swizzle
  const int bn = wgid & 3, bm = wgid >> 2;               // bn-inner: A-panel L2 reuse

  const int t = threadIdx.x;
  const int wid = t >> 6, lane = t & 63;
  const int wm = wid >> 1, wn = wid & 1;
  const int rl = lane & 15, kg = lane >> 4;

  const float* Ag = A + (size_t)bm * 128 * K;
  const unsigned short* Wg = Wb + (size_t)bn * 128 * K;

  f32x4 acc[4][4];
  #pragma unroll
  for (int m=0;m<4;m++)
    #pragma unroll
    for (int n=0;n<4;n++) acc[m][n] = (f32x4){0.f,0.f,0.f,0.f};

  // stage one K-tile into buffer pb: A 128x32 f32 (swizzled), B 128x32 bf16 (swizzled)
  #define STAGE(pb, k0) do {                                                   \
    _Pragma("unroll")                                                          \
    for (int j = 0; j < 4; ++j){                                               \
      int s = j*256 + t; int r = s>>3; int ql = (s&7) ^ (r&7);                 \
      gload16(Ag + (size_t)r*K + (k0) + (ql<<2), &As[pb][(j*4+wid)*256]);      \
    }                                                                          \
    _Pragma("unroll")                                                          \
    for (int j = 0; j < 2; ++j){                                               \
      int s = j*256 + t; int r = s>>2; int ql = (s&3) ^ (r&3);                 \
      gload16(Wg + (size_t)r*K + (k0) + (ql<<3), &Bs[pb][(j*4+wid)*512]);      \
    }                                                                          \
  } while(0)

  STAGE(0, 0);
  asm volatile("s_waitcnt vmcnt(0)" ::: "memory");
  __syncthreads();

  int pc = 0;
  for (int kt = 0; kt < 16; ++kt){
    if (kt < 15) STAGE(pc ^ 1, (kt + 1) * 32);

    s16x8 af[4], bw[4];
    #pragma unroll
    for (int m=0;m<4;m++){
      const int row = wm*64 + m*16 + rl;
      const float* ab = &As[pc][row*32];
      const int q0 = kg*2;
      f32x4 x0 = *(const f32x4*)(ab + ((( q0    ) ^ (row&7)) << 2));
      f32x4 x1 = *(const f32x4*)(ab + (((q0 + 1) ^ (row&7)) << 2));
      af[m] = cvt8(x0, x1);
    }
    #pragma unroll
    for (int n=0;n<4;n++){
      const int row = wn*64 + n*16 + rl;
      bw[n] = *(const s16x8*)&Bs[pc][row*32 + ((kg ^ (row&3)) << 3)];
    }
    #pragma unroll
    for (int m=0;m<4;m++)
      #pragma unroll
      for (int n=0;n<4;n++)
        acc[m][n] = __builtin_amdgcn_mfma_f32_16x16x32_bf16(af[m], bw[n], acc[m][n], 0, 0, 0);

    __syncthreads();   // drains vmcnt (stage done) + protects pc for overwrite
    pc ^= 1;
  }
  #undef STAGE

  #pragma unroll
  for (int n=0;n<4;n++){
    const int gcol = bn*128 + wn*64 + n*16 + rl;
    const float bv = bias[gcol];
    #pragma unroll
    for (int m=0;m<4;m++){
      const int growb = bm*128 + wm*64 + m*16 + kg*4;
      #pragma unroll
      for (int r=0;r<4;r++){
        float v = (acc[m][n][r] + bv) * scale;
        size_t idx = (size_t)(growb + r) * N + gcol;
        if (OUT_BF16) ((unsigned short*)out_)[idx] = f2bf(v);
        else          ((float*)out_)[idx] = v;
      }
    }
  }
}

// partial scores over one ww-chunk: part[wwc][b*512+dd][m] = sum_{ww in chunk} Qp[b,ww,dd]*Kp[b,ww,m,dd]
__global__ __launch_bounds__(256) void scores_kernel(
    const float* __restrict__ Qp, const unsigned short* __restrict__ Kp,
    float* __restrict__ part)
{
  const int wwc = blockIdx.x, ddt = blockIdx.y, b = blockIdx.z;
  const int ww0 = wwc*64, dd0 = ddt*64;
  __shared__ float qs[64][64];
  const int t = threadIdx.x;
  {
    const int dd = t & 63, wbase = t >> 6;
    #pragma unroll
    for (int i=0;i<16;i++){
      int ww = wbase + i*4;
      qs[ww][dd] = Qp[(size_t)(b*512 + ww0 + ww)*512 + dd0 + dd];
    }
  }
  __syncthreads();
  const int g = t & 7, mr = t >> 3;
  float acc[2][8];
  #pragma unroll
  for (int r=0;r<2;r++)
    #pragma unroll
    for (int j=0;j<8;j++) acc[r][j] = 0.f;

  for (int ww=0; ww<64; ww++){
    float4 q0 = *(const float4*)&qs[ww][g*8];
    float4 q1 = *(const float4*)&qs[ww][g*8+4];
    float qv[8] = {q0.x,q0.y,q0.z,q0.w,q1.x,q1.y,q1.z,q1.w};
    #pragma unroll
    for (int r=0;r<2;r++){
      const int m = mr + r*32;
      u16x8 kv = *(const u16x8*)&Kp[((size_t)(b*512 + ww0 + ww)*64 + m)*512 + dd0 + g*8];
      #pragma unroll
      for (int j=0;j<8;j++) acc[r][j] += qv[j] * bf2f(kv[j]);
    }
  }
  #pragma unroll
  for (int r=0;r<2;r++){
    const int m = mr + r*32;
    #pragma unroll
    for (int j=0;j<8;j++){
      const int dd = dd0 + g*8 + j;
      part[(size_t)wwc*131072 + (size_t)(b*512 + dd)*64 + m] = acc[r][j];
    }
  }
}

__global__ __launch_bounds__(256) void softmax_kernel(
    const float* __restrict__ part, float* __restrict__ attn)
{
  const int row = blockIdx.x*4 + (threadIdx.x >> 6);
  const int m = threadIdx.x & 63;
  float v = 0.f;
  #pragma unroll
  for (int c=0;c<8;c++) v += part[(size_t)c*131072 + (size_t)row*64 + m];
  float mx = v;
  #pragma unroll
  for (int o=32;o>=1;o>>=1) mx = fmaxf(mx, __shfl_xor(mx, o));
  float e = __expf(v - mx);
  float s = e;
  #pragma unroll
  for (int o=32;o>=1;o>>=1) s += __shfl_xor(s, o);
  attn[(size_t)row*64 + m] = e / s;
}

__global__ __launch_bounds__(256) void pv_kernel(
    const float* __restrict__ attn, const unsigned short* __restrict__ Vp,
    float* __restrict__ att_out)
{
  const int wwc = blockIdx.x, ddt = blockIdx.y, b = blockIdx.z;
  const int ww0 = wwc*64, dd0 = ddt*64;
  __shared__ float as_[64][72];
  const int t = threadIdx.x;
  {
    const int m = t & 63, dbase = t >> 6;
    #pragma unroll
    for (int i=0;i<16;i++){
      int dd = dbase + i*4;
      as_[m][dd] = attn[(size_t)(b*512 + dd0 + dd)*64 + m];
    }
  }
  __syncthreads();
  const int g = t & 7, wr = t >> 3;
  float acc[2][8];
  #pragma unroll
  for (int r=0;r<2;r++)
    #pragma unroll
    for (int j=0;j<8;j++) acc[r][j] = 0.f;

  for (int m=0;m<64;m++){
    float4 a0 = *(const float4*)&as_[m][g*8];
    float4 a1 = *(const float4*)&as_[m][g*8+4];
    float av[8] = {a0.x,a0.y,a0.z,a0.w,a1.x,a1.y,a1.z,a1.w};
    #pragma unroll
    for (int r=0;r<2;r++){
      const int ww = wr + r*32;
      u16x8 vv = *(const u16x8*)&Vp[((size_t)(b*512 + ww0 + ww)*64 + m)*512 + dd0 + g*8];
      #pragma unroll
      for (int j=0;j<8;j++) acc[r][j] += av[j] * bf2f(vv[j]);
    }
  }
  #pragma unroll
  for (int r=0;r<2;r++){
    const int ww = ww0 + wr + r*32;
    float4 o0 = {acc[r][0],acc[r][1],acc[r][2],acc[r][3]};
    float4 o1 = {acc[r][4],acc[r][5],acc[r][6],acc[r][7]};
    float* dst = &att_out[(size_t)(ww*4 + b)*512 + dd0 + g*8];
    *(float4*)dst = o0;
    *(float4*)(dst+4) = o1;
  }
}

extern "C" void kernel_launch(void* const* d_in, const int* in_sizes, int n_in,
                              void* d_out, int out_size, void* d_ws, size_t ws_size,
                              hipStream_t stream) {
  const float* Q  = (const float*)d_in[0];
  const float* K  = (const float*)d_in[1];
  const float* V  = (const float*)d_in[2];
  const float* Wq = (const float*)d_in[3];
  const float* bq = (const float*)d_in[4];
  const float* Wk = (const float*)d_in[5];
  const float* bk = (const float*)d_in[6];
  const float* Wv = (const float*)d_in[7];
  const float* bv = (const float*)d_in[8];
  const float* Wp = (const float*)d_in[9];
  const float* bp = (const float*)d_in[10];
  float* out = (float*)d_out;

  char* ws = (char*)d_ws;
  float* Qp       = (float*)(ws);                       // 4 MiB
  float* part     = (float*)(ws + ((size_t)4<<20));     // 4 MiB (reused as att_out)
  float* att_out  = part;
  float* attn     = (float*)(ws + ((size_t)8<<20));     // 0.5 MiB
  unsigned short* Wqb = (unsigned short*)(ws + ((size_t)9<<20));
  unsigned short* Wkb = Wqb + 262144;
  unsigned short* Wvb = Wkb + 262144;
  unsigned short* Wpb = Wvb + 262144;                   // 2 MiB total
  unsigned short* KVp = (unsigned short*)(ws + ((size_t)11<<20)); // 128 MiB

  const float qscale = 0.044194173824159223f;  // 1/sqrt(512)

  cast_w<<<512, 256, 0, stream>>>(Wq, Wk, Wv, Wp, Wqb, Wkb, Wvb, Wpb);

  // Q projection (+bias, /sqrt(d)) -> f32
  gemm_f32a<0><<<64, 256, 0, stream>>>(Q, Wqb, bq, qscale, Qp, 2048);
  // K projection -> bf16
  gemm_f32a<1><<<4096, 256, 0, stream>>>(K, Wkb, bk, 1.f, KVp, 131072);
  scores_kernel<<<dim3(8,8,4), 256, 0, stream>>>(Qp, KVp, part);
  softmax_kernel<<<512, 256, 0, stream>>>(part, attn);
  // V projection reuses KVp (stream-ordered after scores)
  gemm_f32a<1><<<4096, 256, 0, stream>>>(V, Wvb, bv, 1.f, KVp, 131072);
  pv_kernel<<<dim3(8,8,4), 256, 0, stream>>>(attn, KVp, att_out);
  // output projection -> d_out
  gemm_f32a<0><<<64, 256, 0, stream>>>(att_out, Wpb, bp, 1.f, out, 2048);
}